// Round 3
// baseline (201.707 us; speedup 1.0000x reference)
//
#include <hip/hip_runtime.h>
#include <hip/hip_bf16.h>
#include <math.h>

#define SEQ_LEN 32768
#define HID 1024
#define NBLK 1024   // == SEQ_LEN/32 == HID, both by construction

// ws layout (floats): v[1024] | bstats float2[1024] (=2048 floats) | ctl (16 KB)
#define CTL_OFF_FLOATS (HID + 2 * 1024)
#define CTL_BYTES 16384
// per-barrier block: 2048 unsigned (8 KB): sub[i] at i*32 (i<32), master at 1024, flag at 1056

// ---------------------------------------------------------------------------
// Hierarchical device-scope grid barrier. All 1024 blocks are co-resident
// (4 blocks/CU x 256 CU, enforced by __launch_bounds__(256,4): VGPR<=128,
// LDS ~2.5KB), so spinning is safe. 32 sub-counters avoid same-line
// serialization of 1024 atomicAdds; release-sequence through acq_rel RMWs
// gives transitive visibility of all blocks' prior writes.
// ---------------------------------------------------------------------------
__device__ __forceinline__ void grid_bar(unsigned* base, int t, int bid) {
    __syncthreads();
    if (t == 0) {
        unsigned* sub    = base + ((bid & 31) << 5);
        unsigned* master = base + 1024;
        unsigned* flag   = base + 1056;
        unsigned o = __hip_atomic_fetch_add(sub, 1u, __ATOMIC_ACQ_REL, __HIP_MEMORY_SCOPE_AGENT);
        if (o == 31u) {
            unsigned om = __hip_atomic_fetch_add(master, 1u, __ATOMIC_ACQ_REL, __HIP_MEMORY_SCOPE_AGENT);
            if (om == 31u)
                __hip_atomic_store(flag, 1u, __ATOMIC_RELEASE, __HIP_MEMORY_SCOPE_AGENT);
        }
        while (__hip_atomic_load(flag, __ATOMIC_ACQUIRE, __HIP_MEMORY_SCOPE_AGENT) == 0u)
            __builtin_amdgcn_s_sleep(8);
    }
    __syncthreads();
    asm volatile("" ::: "memory");
}

__global__ void __launch_bounds__(256, 4)
k_fused(const float* __restrict__ W, const float* __restrict__ hvec,
        const float* __restrict__ enc, float* __restrict__ v,
        float2* __restrict__ bstats, unsigned* __restrict__ ctl,
        float* __restrict__ out) {
    const int t = threadIdx.x;
    const int bid = blockIdx.x;
    const int wave = t >> 6;
    const int lane = t & 63;

    __shared__ float red[4];
    __shared__ float wm[4], wz[4];
    __shared__ float e_lds[32];
    __shared__ float sm[256], sz[256];

    // ---- Phase 1: v[col] = sum_d hvec[d] * W[d*H + col] -------------------
    // XCD-folded column map: blocks on the same XCD (bid%8) own 128
    // consecutive columns, so W cachelines are shared within one XCD L2.
    {
        const int col = ((bid & 7) << 7) + (bid >> 3);
        float acc = 0.f;
#pragma unroll
        for (int i = 0; i < 4; ++i) {
            const int d = (i << 8) + t;
            acc = fmaf(hvec[d], W[d * HID + col], acc);
        }
#pragma unroll
        for (int off = 32; off; off >>= 1) acc += __shfl_xor(acc, off, 64);
        if ((t & 63) == 0) red[t >> 6] = acc;
        __syncthreads();
        if (t == 0) v[col] = (red[0] + red[1]) + (red[2] + red[3]);
    }

    grid_bar(ctl, t, bid);                 // v fully published

    // ---- Phase 2: energies for rows [bid*32, bid*32+32) -------------------
    // Each wave: 8 rows, 64 lanes x 4 float4 per row (coalesced 4KB/row),
    // software-pipelined next-row loads. Energies stay in LDS; per-block
    // online (m,z) -> bstats[bid].
    {
        const int row0 = (bid << 5) + (wave << 3);
        const float4 vr0 = *reinterpret_cast<const float4*>(v +       (lane << 2));
        const float4 vr1 = *reinterpret_cast<const float4*>(v + 256 + (lane << 2));
        const float4 vr2 = *reinterpret_cast<const float4*>(v + 512 + (lane << 2));
        const float4 vr3 = *reinterpret_cast<const float4*>(v + 768 + (lane << 2));

        float m = -__builtin_inff();
        float z = 0.f;

        const float4* p = reinterpret_cast<const float4*>(enc + (size_t)row0 * HID) + lane;
        float4 a = p[0], b = p[64], c = p[128], d = p[192];

#pragma unroll
        for (int r = 0; r < 8; ++r) {
            float4 na, nb, nc, nd;
            if (r < 7) {
                const float4* q = p + (size_t)(r + 1) * 256;
                na = q[0]; nb = q[64]; nc = q[128]; nd = q[192];
            }
            float acc = a.x * vr0.x + a.y * vr0.y + a.z * vr0.z + a.w * vr0.w
                      + b.x * vr1.x + b.y * vr1.y + b.z * vr1.z + b.w * vr1.w
                      + c.x * vr2.x + c.y * vr2.y + c.z * vr2.z + c.w * vr2.w
                      + d.x * vr3.x + d.y * vr3.y + d.z * vr3.z + d.w * vr3.w;
#pragma unroll
            for (int off = 32; off; off >>= 1) acc += __shfl_xor(acc, off, 64);
            if (lane == 0) e_lds[(wave << 3) + r] = acc;
            const float nm = fmaxf(m, acc);
            z = z * __expf(m - nm) + __expf(acc - nm);
            m = nm;
            a = na; b = nb; c = nc; d = nd;
        }

        if (lane == 0) { wm[wave] = m; wz[wave] = z; }
        __syncthreads();
        if (t == 0) {
            float M = fmaxf(fmaxf(wm[0], wm[1]), fmaxf(wm[2], wm[3]));
            float Z = wz[0] * __expf(wm[0] - M) + wz[1] * __expf(wm[1] - M)
                    + wz[2] * __expf(wm[2] - M) + wz[3] * __expf(wm[3] - M);
            bstats[bid] = make_float2(M, Z);
        }
    }

    grid_bar(ctl + 2048, t, bid);          // all bstats published

    // ---- Phase 3: global (M,Z) from bstats (redundant per block, 8KB L2-hot),
    // then write this block's 32 outputs from e_lds. ------------------------
    {
        float m = -__builtin_inff();
        float z = 0.f;
#pragma unroll
        for (int i = 0; i < 4; ++i) {
            const float2 s = bstats[t + (i << 8)];
            const float nm = fmaxf(m, s.x);
            z = z * __expf(m - nm) + s.y * __expf(s.x - nm);
            m = nm;
        }
        sm[t] = m; sz[t] = z;
        __syncthreads();
        for (int off = 128; off; off >>= 1) {
            if (t < off) {
                const float m1 = sm[t], z1 = sz[t];
                const float m2 = sm[t + off], z2 = sz[t + off];
                const float M = fmaxf(m1, m2);
                sm[t] = M;
                sz[t] = z1 * __expf(m1 - M) + z2 * __expf(m2 - M);
            }
            __syncthreads();
        }
        const float M = sm[0];
        const float rZ = 1.f / sz[0];
        if (t < 32) out[(bid << 5) + t] = __expf(e_lds[t] - M) * rZ;
    }
}

extern "C" void kernel_launch(void* const* d_in, const int* in_sizes, int n_in,
                              void* d_out, int out_size, void* d_ws, size_t ws_size,
                              hipStream_t stream) {
    const float* hidden = (const float*)d_in[0];   // [1,1,1024]
    const float* enc    = (const float*)d_in[1];   // [32768,1024]
    const float* W      = (const float*)d_in[2];   // [1024,1024]
    // d_in[3] (bias) cancels in softmax (constant shift) — never read.

    float* ws      = (float*)d_ws;
    float* v       = ws;                                  // 1024 floats
    float2* bstats = (float2*)(ws + HID);                 // 1024 float2
    unsigned* ctl  = (unsigned*)(ws + CTL_OFF_FLOATS);    // 16 KB barrier state

    // Zero barrier state every call (captured in the graph -> deterministic
    // across replays; also fixes the initial 0xAA poison).
    hipMemsetAsync(ctl, 0, CTL_BYTES, stream);

    k_fused<<<NBLK, 256, 0, stream>>>(W, hidden, enc, v, bstats, ctl, (float*)d_out);
}

// Round 4
// 42.128 us; speedup vs baseline: 4.7880x; 4.7880x over previous
//
#include <hip/hip_runtime.h>
#include <hip/hip_bf16.h>
#include <math.h>

#define SEQ_LEN 32768
#define HID 1024
#define NBLK 1024   // == SEQ_LEN/32 == HID

// ws layout (floats): v[1024] | bstats float2[1024] | ctl (8 KB)
#define CTL_OFF_FLOATS (HID + 2 * 1024)
#define CTL_BYTES 8192
// ctl (unsigned): sub[i] at i*32 (i<32), master at 1024, flag at 1056

// ---------------------------------------------------------------------------
// K1: v = W^T h. One block per column, 256 threads, wave shfl + LDS combine.
// Separate dispatch, so consumers see v through the normal inter-dispatch
// release/acquire — no manual coherence needed for v.
// ---------------------------------------------------------------------------
__global__ void __launch_bounds__(256) k_matvec(const float* __restrict__ W,
                                                const float* __restrict__ hvec,
                                                float* __restrict__ v) {
    const int col = blockIdx.x;
    const int t = threadIdx.x;
    float acc = 0.f;
#pragma unroll
    for (int i = 0; i < 4; ++i) {
        const int d = (i << 8) + t;
        acc = fmaf(hvec[d], W[d * HID + col], acc);
    }
#pragma unroll
    for (int off = 32; off; off >>= 1) acc += __shfl_xor(acc, off, 64);
    __shared__ float red[4];
    if ((t & 63) == 0) red[t >> 6] = acc;
    __syncthreads();
    if (t == 0) v[col] = (red[0] + red[1]) + (red[2] + red[3]);
}

// ---------------------------------------------------------------------------
// K2: energies + single relaxed grid barrier + softmax finalize.
// 1024 blocks x 256 threads, __launch_bounds__(256,4): grid capacity
// 256 CU x >=4 blk/CU >= 1024 -> all blocks co-resident, spin is safe.
//
// COHERENCE DESIGN (the round-3 lesson): no acquire/release anywhere.
// Agent-scope RELAXED atomics are performed at the MALL (sc1) without L2
// writeback/invalidate. bstats is published/consumed ONLY via relaxed
// agent-scope u64 atomics. Ordering "my bstats store completed before my
// arrival RMW" is enforced by s_waitcnt vmcnt(0) in the arriving thread;
// the MALL's same-line serialization of the counter RMWs makes the flag
// transitively ordered after all 1024 publications.
// ---------------------------------------------------------------------------
__global__ void __launch_bounds__(256, 4)
k_energy_final(const float* __restrict__ enc, const float* __restrict__ v,
               unsigned long long* __restrict__ bstats,
               unsigned* __restrict__ ctl, float* __restrict__ out) {
    const int t = threadIdx.x;
    const int bid = blockIdx.x;
    const int wave = t >> 6;
    const int lane = t & 63;

    __shared__ float wm[4], wz[4];
    __shared__ float e_lds[32];
    __shared__ float sm[256], sz[256];

    // ---- energies for rows [bid*32, bid*32+32) ----------------------------
    {
        const int row0 = (bid << 5) + (wave << 3);
        const float4 vr0 = *reinterpret_cast<const float4*>(v +       (lane << 2));
        const float4 vr1 = *reinterpret_cast<const float4*>(v + 256 + (lane << 2));
        const float4 vr2 = *reinterpret_cast<const float4*>(v + 512 + (lane << 2));
        const float4 vr3 = *reinterpret_cast<const float4*>(v + 768 + (lane << 2));

        float m = -__builtin_inff();
        float z = 0.f;

        const float4* p = reinterpret_cast<const float4*>(enc + (size_t)row0 * HID) + lane;
        float4 a = p[0], b = p[64], c = p[128], d = p[192];

#pragma unroll
        for (int r = 0; r < 8; ++r) {
            float4 na, nb, nc, nd;
            if (r < 7) {
                const float4* q = p + (size_t)(r + 1) * 256;
                na = q[0]; nb = q[64]; nc = q[128]; nd = q[192];
            }
            float acc = a.x * vr0.x + a.y * vr0.y + a.z * vr0.z + a.w * vr0.w
                      + b.x * vr1.x + b.y * vr1.y + b.z * vr1.z + b.w * vr1.w
                      + c.x * vr2.x + c.y * vr2.y + c.z * vr2.z + c.w * vr2.w
                      + d.x * vr3.x + d.y * vr3.y + d.z * vr3.z + d.w * vr3.w;
#pragma unroll
            for (int off = 32; off; off >>= 1) acc += __shfl_xor(acc, off, 64);
            if (lane == 0) e_lds[(wave << 3) + r] = acc;
            const float nm = fmaxf(m, acc);
            z = z * __expf(m - nm) + __expf(acc - nm);
            m = nm;
            a = na; b = nb; c = nc; d = nd;
        }

        if (lane == 0) { wm[wave] = m; wz[wave] = z; }
    }
    __syncthreads();

    // ---- publish bstats[bid], arrive, spin (all RELAXED, agent scope) -----
    if (t == 0) {
        const float M = fmaxf(fmaxf(wm[0], wm[1]), fmaxf(wm[2], wm[3]));
        const float Z = wz[0] * __expf(wm[0] - M) + wz[1] * __expf(wm[1] - M)
                      + wz[2] * __expf(wm[2] - M) + wz[3] * __expf(wm[3] - M);
        const float2 s = make_float2(M, Z);
        __hip_atomic_store(bstats + bid, __builtin_bit_cast(unsigned long long, s),
                           __ATOMIC_RELAXED, __HIP_MEMORY_SCOPE_AGENT);
        // my publication must complete at the MALL before my arrival RMW
        asm volatile("s_waitcnt vmcnt(0)" ::: "memory");

        unsigned* sub    = ctl + ((bid & 31) << 5);
        unsigned* master = ctl + 1024;
        unsigned* flag   = ctl + 1056;
        const unsigned o = __hip_atomic_fetch_add(sub, 1u, __ATOMIC_RELAXED,
                                                  __HIP_MEMORY_SCOPE_AGENT);
        if (o == 31u) {
            const unsigned om = __hip_atomic_fetch_add(master, 1u, __ATOMIC_RELAXED,
                                                       __HIP_MEMORY_SCOPE_AGENT);
            if (om == 31u)
                __hip_atomic_store(flag, 1u, __ATOMIC_RELAXED, __HIP_MEMORY_SCOPE_AGENT);
        }
        while (__hip_atomic_load(flag, __ATOMIC_RELAXED, __HIP_MEMORY_SCOPE_AGENT) == 0u)
            __builtin_amdgcn_s_sleep(2);
    }
    __syncthreads();
    asm volatile("" ::: "memory");

    // ---- global (M,Z): redundant per-block reduce of 8 KB bstats ----------
    {
        float m = -__builtin_inff();
        float z = 0.f;
#pragma unroll
        for (int i = 0; i < 4; ++i) {
            const unsigned long long bits =
                __hip_atomic_load(bstats + t + (i << 8), __ATOMIC_RELAXED,
                                  __HIP_MEMORY_SCOPE_AGENT);
            const float2 s = __builtin_bit_cast(float2, bits);
            const float nm = fmaxf(m, s.x);
            z = z * __expf(m - nm) + s.y * __expf(s.x - nm);
            m = nm;
        }
        sm[t] = m; sz[t] = z;
        __syncthreads();
        for (int off = 128; off; off >>= 1) {
            if (t < off) {
                const float m1 = sm[t], z1 = sz[t];
                const float m2 = sm[t + off], z2 = sz[t + off];
                const float M = fmaxf(m1, m2);
                sm[t] = M;
                sz[t] = z1 * __expf(m1 - M) + z2 * __expf(m2 - M);
            }
            __syncthreads();
        }
        const float M = sm[0];
        const float rZ = 1.f / sz[0];
        if (t < 32) out[(bid << 5) + t] = __expf(e_lds[t] - M) * rZ;
    }
}

extern "C" void kernel_launch(void* const* d_in, const int* in_sizes, int n_in,
                              void* d_out, int out_size, void* d_ws, size_t ws_size,
                              hipStream_t stream) {
    const float* hidden = (const float*)d_in[0];   // [1,1,1024]
    const float* enc    = (const float*)d_in[1];   // [32768,1024]
    const float* W      = (const float*)d_in[2];   // [1024,1024]
    // d_in[3] (bias) cancels in softmax (constant shift) — never read.

    float* ws = (float*)d_ws;
    float* v  = ws;                                           // 1024 floats
    unsigned long long* bstats = (unsigned long long*)(ws + HID); // 1024 u64
    unsigned* ctl = (unsigned*)(ws + CTL_OFF_FLOATS);         // 8 KB

    hipMemsetAsync(ctl, 0, CTL_BYTES, stream);                // barrier state = 0
    k_matvec<<<HID, 256, 0, stream>>>(W, hidden, v);
    k_energy_final<<<NBLK, 256, 0, stream>>>(enc, v, bstats, ctl, (float*)d_out);
}